// Round 7
// baseline (1591.330 us; speedup 1.0000x reference)
//
#include <hip/hip_runtime.h>
#include <hip/hip_bf16.h>

#define Bb 4
#define Nn 384
#define Ee 768
#define Hh 32
#define Ff 3072
#define Ll 12
#define Ss 512
#define Mm (Nn*Bb)   // 1536 tokens

typedef __attribute__((ext_vector_type(8))) short bf16x8;
typedef __attribute__((ext_vector_type(4))) float f32x4;
typedef unsigned short u16;

__device__ __forceinline__ u16 f2b(float f) {
  union { float f; unsigned int i; } c; c.f = f;
  unsigned int x = c.i;
  return (u16)((x + 0x7fffu + ((x >> 16) & 1u)) >> 16); // RNE
}
__device__ __forceinline__ float b2f(u16 u) {
  union { unsigned int i; float f; } c; c.i = ((unsigned int)u) << 16; return c.f;
}
__device__ __forceinline__ unsigned pkcvt(float lo, float hi) {
  unsigned r;
  asm("v_cvt_pk_bf16_f32 %0, %1, %2" : "=v"(r) : "v"(lo), "v"(hi));
  return r;
}
__device__ __forceinline__ void gload_lds16(const void* g, void* l) {
  __builtin_amdgcn_global_load_lds((__attribute__((address_space(1))) void*)(g),
                                   (__attribute__((address_space(3))) void*)(l), 16, 0, 0);
}

// ---------------- embedding
__global__ __launch_bounds__(256) void embed_kernel(
    const int* __restrict__ node_type, const float* __restrict__ nif,
    const int* __restrict__ in_deg, const int* __restrict__ out_deg,
    const float* __restrict__ node_emb, const float* __restrict__ ind_emb,
    const float* __restrict__ outd_emb,
    float* __restrict__ x, u16* __restrict__ xb)
{
  const int r = blockIdx.x;           // r = n*B + b
  const int n = r / Bb, b = r % Bb;
  const int nt  = node_type[b*Nn + n];
  const int idg = in_deg[b*Nn + n];
  const int odg = out_deg[b*Nn + n];
  for (int c = threadIdx.x; c < Ee; c += 256) {
    float val = node_emb[(size_t)nt*Ee + c] + ind_emb[(size_t)idg*Ee + c]
              + outd_emb[(size_t)odg*Ee + c] + nif[((size_t)b*Nn + n)*Ee + c];
    x[(size_t)r*Ee + c] = val;
    xb[(size_t)r*Ee + c] = f2b(val);
  }
}

// ---------------- spatial_pos transpose
__global__ void spT_kernel(const int* __restrict__ sp, int* __restrict__ spT)
{
  __shared__ int tile[32][33];
  const int b = blockIdx.z;
  const int n0 = blockIdx.y * 32, m0 = blockIdx.x * 32;
  const int tx = threadIdx.x, ty = threadIdx.y;
  for (int i = ty; i < 32; i += 8)
    tile[i][tx] = sp[((size_t)b*Nn + n0 + i)*Nn + m0 + tx];
  __syncthreads();
  for (int i = ty; i < 32; i += 8)
    spT[((size_t)b*Nn + m0 + i)*Nn + n0 + tx] = tile[tx][i];
}

// ---------------- bias precompute into MFMA-fragment chunk layout
__global__ __launch_bounds__(256) void bias_pre_kernel(
    const float* __restrict__ atb, const int* __restrict__ sp, const int* __restrict__ spT,
    const float* __restrict__ sp_emb, const float* __restrict__ sp_emb_rev,
    u16* __restrict__ biasb)
{
  __shared__ float spc[512], sprc[512];
  const int bx = blockIdx.x, h = blockIdx.y, b = blockIdx.z;
  const int t = threadIdx.x;
  for (int i = t; i < 512; i += 256) {
    spc[i]  = sp_emb[(size_t)i*Hh + h];
    sprc[i] = sp_emb_rev[(size_t)i*Hh + h];
  }
  __syncthreads();
  const int q = bx*16 + ((t >> 2) & 15);
  const size_t rowb = ((size_t)b*Nn + q)*Nn;
  u16* outb = biasb + (((size_t)(b*Hh + h)*24 + bx)*24)*256 + t;
  const int mbase = ((t >> 6) << 2) + (t & 3);
  for (int tt = 0; tt < 24; ++tt) {
    const int m = tt*16 + mbase;
    float v = atb[rowb + m] + spc[sp[rowb + m]] + sprc[spT[rowb + m]];
    outb[tt*256] = f2b(v);
  }
}

// ---------------- weight convert to k8-interleaved layout: wT[kb][n][8] bf16
// (kb = k/8). Streaming: gload_lds 8x256 f32 band -> conflict-free column reads
// -> pkcvt -> fully contiguous 16B-chunk writes. No transpose through LDS strides.
__device__ __forceinline__ void wc3_resolve(int tid, int layer,
    const float* Wq, const float* Wk, const float* Wv, const float* Wo,
    const float* W1, const float* W2, u16* slot,
    const float*& src, u16*& dst, int& Ns, int& kb, int& nc)
{
  if (tid < 1152)      { int seg = tid/288; int r = tid - seg*288;
                         src = (seg==0?Wq:(seg==1?Wk:(seg==2?Wv:Wo))) + (size_t)layer*Ee*Ee;
                         dst = slot + (size_t)(seg<3 ? seg*589824 : 1769472);
                         Ns = 768; kb = r/3; nc = r%3; }
  else if (tid < 2304) { int r = tid-1152; src = W1 + (size_t)layer*Ee*Ff;
                         dst = slot + 2359296; Ns = 3072; kb = r/12; nc = r%12; }
  else                 { int r = tid-2304; src = W2 + (size_t)layer*Ff*Ee;
                         dst = slot + 4718592; Ns = 768;  kb = r/3;  nc = r%3; }
}

__global__ __launch_bounds__(256) void wconv_kernel(
    const float* __restrict__ Wq, const float* __restrict__ Wk, const float* __restrict__ Wv,
    const float* __restrict__ Wo, const float* __restrict__ W1, const float* __restrict__ W2,
    int layer0, u16* __restrict__ wTall, unsigned slotStride)
{
  __shared__ __align__(16) float buf[2][2048];     // 2 x 8KB (8 rows x 256 cols)
  const int t = threadIdx.x;
  const int layer = layer0 + blockIdx.y;
  u16* slot = wTall + (size_t)blockIdx.y * slotStride;
  const int tid0 = blockIdx.x * 8;
  const int lrow = t >> 6, lcol = (t & 63) << 2;   // staging coords (4 rows/inst)

  const float* src; u16* dst; int Ns, kb, nc;
  wc3_resolve(tid0, layer, Wq, Wk, Wv, Wo, W1, W2, slot, src, dst, Ns, kb, nc);
  #pragma unroll
  for (int i = 0; i < 2; ++i)
    gload_lds16(src + (size_t)(kb*8 + i*4 + lrow)*Ns + nc*256 + lcol,
                (char*)&buf[0][0] + i*4096 + t*16);

  for (int it = 0; it < 8; ++it) {
    const int cur = it & 1;
    u16* dstC = dst; const int NsC = Ns, kbC = kb, ncC = nc;
    if (it + 1 < 8) {
      wc3_resolve(tid0 + it + 1, layer, Wq, Wk, Wv, Wo, W1, W2, slot, src, dst, Ns, kb, nc);
      #pragma unroll
      for (int i = 0; i < 2; ++i)
        gload_lds16(src + (size_t)(kb*8 + i*4 + lrow)*Ns + nc*256 + lcol,
                    (char*)&buf[cur^1][0] + i*4096 + t*16);
      asm volatile("s_waitcnt vmcnt(2)" ::: "memory");   // current tile landed
    } else {
      asm volatile("s_waitcnt vmcnt(0)" ::: "memory");
    }
    __builtin_amdgcn_s_barrier();
    // convert: thread t owns column n' = t; LDS reads bank = t mod 32 (2-way, free)
    const float* bc = &buf[cur][0];
    uint4 u;
    u.x = pkcvt(bc[0*256 + t], bc[1*256 + t]);
    u.y = pkcvt(bc[2*256 + t], bc[3*256 + t]);
    u.z = pkcvt(bc[4*256 + t], bc[5*256 + t]);
    u.w = pkcvt(bc[6*256 + t], bc[7*256 + t]);
    *(uint4*)(dstC + (size_t)kbC*NsC*8 + (size_t)(ncC*256 + t)*8) = u;
    __builtin_amdgcn_s_barrier();            // protect buf[cur] before reuse
  }
}

// ---------------- 128x64-tile GEMM (r5 shape), BK=64, counted-vmcnt 2-barrier pipeline,
// XCD-swizzled. A: [M][K] bf16 linear rows + XOR slot swizzle (rule #21).
// B: k8-interleaved wT[kb][n][8] — staging is contiguous 1KB/inst, frag = 1 b128.
// EPI 0: qkv fused bias (Q scaled) -> bf16 out ld 2304
// EPI 1: f32 partial out ld 768 (z==0 adds bias + residual)
// EPI 2: gelu -> bf16 out ld 3072
template<int EPI>
__global__ __launch_bounds__(256) void gemm3_kernel(
    const u16* __restrict__ A, const u16* __restrict__ Bw,
    const float* __restrict__ b0, const float* __restrict__ b1, const float* __restrict__ b2,
    const float* __restrict__ resid,
    int Kfull, int Ns8, int Kc, float scaleQ,
    float* __restrict__ outF, u16* __restrict__ outB)
{
  __shared__ __align__(16) u16 As[2][128][64];
  __shared__ __align__(16) u16 Bs[2][4096];
  const int t = threadIdx.x, lane = t & 63, wave = t >> 6;
  int bx = blockIdx.x, by = blockIdx.y;
  { // XCD swizzle (xy grid always divisible by 8)
    const int gx = gridDim.x;
    const int nwg = gx * gridDim.y;
    const int bid = bx + gx * by;
    const int cpx = nwg >> 3;
    const int s = (bid & 7) * cpx + (bid >> 3);
    bx = s % gx; by = s / gx;
  }
  const int m0 = bx * 128, n0 = by * 64;
  const int k0 = blockIdx.z * Kc;
  const int wm = wave >> 1, wn = wave & 1;
  const int ql = lane & 15, hi = lane >> 4;
  const int nk = Kc >> 6;
  // EPI0 segment (tiles never straddle 768-col segments)
  int n0loc = n0; size_t bsegoff = 0;
  if (EPI == 0) { const int seg = n0 / 768; n0loc = n0 - seg*768; bsegoff = (size_t)seg*589824; }
  // A staging map: thread t covers rows sr + 32i, slot (t&7), source slot XOR'd
  const int sr = t >> 3;
  const int sslot = (t & 7) ^ (sr & 7);
  const size_t aoff = (size_t)(m0 + sr)*Kfull + k0 + (sslot << 3);
  const size_t rstep = (size_t)32 * Kfull;
  // B staging map: 2 chunks per thread: c = t, t+256; chunk = (kbL, j), XOR'd source n
  const int c0kb = t >> 6,        c0j = t & 63;
  const int c1kb = (t + 256) >> 6, c1j = t & 63;
  const size_t bo0 = bsegoff + (size_t)c0kb*Ns8 + (size_t)(n0loc + (c0j ^ (c0kb & 7)))*8;
  const size_t bo1 = bsegoff + (size_t)c1kb*Ns8 + (size_t)(n0loc + (c1j ^ (c1kb & 7)))*8;
  const int kb0base = k0 >> 3;

  // fragment LDS byte offsets
  int aro[4][2], bro[2][2];
  #pragma unroll
  for (int ks = 0; ks < 2; ++ks) {
    const int kbA = (((ks<<2) + hi) ^ (ql & 7)) << 4;
    #pragma unroll
    for (int f = 0; f < 4; ++f) aro[f][ks] = (wm*64 + f*16 + ql)*128 + kbA;
    #pragma unroll
    for (int f = 0; f < 2; ++f) {
      const int kbB = (ks<<2) + hi;
      bro[f][ks] = ((kbB*64) + ((wn*32 + f*16 + ql) ^ kbB)) << 4;
    }
  }

  f32x4 acc[4][2];
  #pragma unroll
  for (int a = 0; a < 4; ++a)
    #pragma unroll
    for (int c = 0; c < 2; ++c) acc[a][c] = (f32x4){0.f,0.f,0.f,0.f};

  // prologue: issue tile 0
  #pragma unroll
  for (int i = 0; i < 4; ++i)
    gload_lds16(A + aoff + i*rstep, (char*)&As[0][0][0] + i*4096 + t*16);
  gload_lds16(Bw + (size_t)kb0base*Ns8 + bo0, (char*)&Bs[0][0] + t*16);
  gload_lds16(Bw + (size_t)kb0base*Ns8 + bo1, (char*)&Bs[0][0] + 4096 + t*16);

  for (int kt = 0; kt < nk; ++kt) {
    const int cur = kt & 1, nxt = cur ^ 1;
    const bool pre = (kt + 1 < nk);
    if (pre) {
      const size_t kk = (size_t)(kt + 1) << 6;
      #pragma unroll
      for (int i = 0; i < 4; ++i)
        gload_lds16(A + aoff + kk + i*rstep, (char*)&As[nxt][0][0] + i*4096 + t*16);
      const size_t kbrow = (size_t)(kb0base + (kt + 1)*8)*Ns8;
      gload_lds16(Bw + kbrow + bo0, (char*)&Bs[nxt][0] + t*16);
      gload_lds16(Bw + kbrow + bo1, (char*)&Bs[nxt][0] + 4096 + t*16);
      asm volatile("s_waitcnt vmcnt(6)" ::: "memory");   // tile kt landed; kt+1 in flight
    } else {
      asm volatile("s_waitcnt vmcnt(0)" ::: "memory");
    }
    __builtin_amdgcn_s_barrier();            // B1
    __builtin_amdgcn_sched_barrier(0);

    const char* aBase = (const char*)&As[cur][0][0];
    const char* bBase = (const char*)&Bs[cur][0];
    bf16x8 af[4][2], bf[2][2];
    #pragma unroll
    for (int f = 0; f < 4; ++f)
      #pragma unroll
      for (int ks = 0; ks < 2; ++ks)
        af[f][ks] = *(const bf16x8*)(aBase + aro[f][ks]);
    #pragma unroll
    for (int f = 0; f < 2; ++f)
      #pragma unroll
      for (int ks = 0; ks < 2; ++ks)
        bf[f][ks] = *(const bf16x8*)(bBase + bro[f][ks]);
    #pragma unroll
    for (int ks = 0; ks < 2; ++ks)
      #pragma unroll
      for (int fm = 0; fm < 4; ++fm)
        #pragma unroll
        for (int fn = 0; fn < 2; ++fn)
          acc[fm][fn] = __builtin_amdgcn_mfma_f32_16x16x32_bf16(af[fm][ks], bf[fn][ks], acc[fm][fn], 0, 0, 0);
    if (pre) {
      __builtin_amdgcn_sched_barrier(0);
      __builtin_amdgcn_s_barrier();          // B2: cur reads drained before overwrite
    }
  }

  #pragma unroll
  for (int fm = 0; fm < 4; ++fm) {
    const int rowb = m0 + wm*64 + fm*16 + hi*4;
    #pragma unroll
    for (int fn = 0; fn < 2; ++fn) {
      const int gcol = n0 + wn*32 + fn*16 + ql;
      float bv = 0.f, scale = 1.0f;
      if (EPI == 0) {
        const int seg = gcol / 768;
        const int cw = gcol - seg*768;
        bv = (seg == 0) ? b0[cw] : ((seg == 1) ? b1[cw] : b2[cw]);
        if (seg == 0) scale = scaleQ;
      } else if (EPI == 1) {
        bv = (blockIdx.z == 0) ? b0[gcol] : 0.0f;
      } else {
        bv = b0[gcol];
      }
      f32x4 v = acc[fm][fn];
      #pragma unroll
      for (int j = 0; j < 4; ++j) {
        float val = (v[j] + bv) * scale;
        if (EPI == 0) {
          outB[(size_t)(rowb + j) * 2304 + gcol] = f2b(val);
        } else if (EPI == 1) {
          if (blockIdx.z == 0) val += resid[(size_t)(rowb + j) * 768 + gcol];
          outF[(size_t)blockIdx.z * (Mm*768) + (size_t)(rowb + j) * 768 + gcol] = val;
        } else {
          float arg = 0.7978845608028654f * (val + 0.044715f * val * val * val);
          float e = __expf(2.0f * arg);
          float g = 0.5f * val * (2.0f - 2.0f / (e + 1.0f));
          outB[(size_t)(rowb + j) * 3072 + gcol] = f2b(g);
        }
      }
    }
  }
}

// ---------------- MFMA attention: block = (b, h, pair of 64-q-row tiles)
template<int PREBIAS>
__global__ __launch_bounds__(256) void attn2_kernel(
    const u16* __restrict__ qkv,         // [1536][2304] bf16 q|k|v (q pre-scaled)
    const u16* __restrict__ biasb,       // chunk layout (PREBIAS=1)
    const float* __restrict__ atb, const int* __restrict__ sp, const int* __restrict__ spT,
    const float* __restrict__ sp_emb, const float* __restrict__ sp_emb_rev,
    u16* __restrict__ ab)                // [1536][768] bf16
{
  __shared__ __align__(16) u16 Kt[384][32];   // [m][d(24)+pad]
  __shared__ __align__(16) u16 Vt[32][392];   // [d(24)+pad][m] transposed
  __shared__ __align__(16) u16 Qt[64][32];
  __shared__ __align__(16) u16 Pw[4][16][32]; // per-wave P chunk
  __shared__ float spc[512], sprc[512];
  const int bid = blockIdx.x;
  const int pair = bid % 3;
  const int h = (bid / 3) % Hh;
  const int b = bid / (3 * Hh);
  const int t = threadIdx.x, lane = t & 63, wave = t >> 6;
  const int ql = lane & 15, hi = lane >> 4;

  for (int idx = t; idx < 384*6; idx += 256) {
    const int m = idx / 6, c = idx - m*6;
    const u16* base = qkv + ((size_t)m*Bb + b)*2304 + h*24 + c*4;
    uint2 kk = *(const uint2*)(base + 768);
    uint2 vv = *(const uint2*)(base + 1536);
    *(uint2*)&Kt[m][c*4] = kk;
    Vt[c*4+0][m] = (u16)(vv.x & 0xffffu); Vt[c*4+1][m] = (u16)(vv.x >> 16);
    Vt[c*4+2][m] = (u16)(vv.y & 0xffffu); Vt[c*4+3][m] = (u16)(vv.y >> 16);
  }
  for (int idx = t; idx < 384*2; idx += 256)           // K d-pad
    *(uint2*)&Kt[idx>>1][24 + (idx&1)*4] = make_uint2(0u, 0u);
  for (int idx = t; idx < 8*196; idx += 256)           // V^T d-pad rows
    *(unsigned*)((char*)&Vt[24][0] + idx*4) = 0u;
  for (int idx = t; idx < 64*2; idx += 256)            // Q d-pad
    *(uint2*)&Qt[idx>>1][24 + (idx&1)*4] = make_uint2(0u, 0u);
  if (!PREBIAS) {
    for (int i = t; i < 512; i += 256) {
      spc[i]  = sp_emb[(size_t)i*Hh + h];
      sprc[i] = sp_emb_rev[(size_t)i*Hh + h];
    }
  }

  for (int qi = 0; qi < 2; ++qi) {
    const int ntile = pair*2 + qi;
    for (int idx = t; idx < 64*6; idx += 256) {
      const int qr = idx / 6, c = idx - qr*6;
      const u16* base = qkv + ((size_t)(ntile*64 + qr)*Bb + b)*2304 + h*24 + c*4;
      *(uint2*)&Qt[qr][c*4] = *(const uint2*)base;
    }
    __syncthreads();   // covers K/V staging (iter 0) and Qt restage

    const int q0 = ntile*64 + wave*16;
    const int q = q0 + ql;
    const bf16x8 qf = *(const bf16x8*)&Qt[wave*16 + ql][hi*8];

    f32x4 f[24];
    const u16* bp = biasb + (((size_t)(b*Hh + h)*24 + ntile*4 + wave)*24)*256 + lane*4;
    const size_t crow = ((size_t)b*Nn + q)*Nn;
    #pragma unroll
    for (int tt = 0; tt < 24; ++tt) {
      bf16x8 kf = *(const bf16x8*)&Kt[tt*16 + ql][hi*8];
      f32x4 z = (f32x4){0.f,0.f,0.f,0.f};
      f32x4 s = __builtin_amdgcn_mfma_f32_16x16x32_bf16(kf, qf, z, 0, 0, 0);
      if (PREBIAS) {
        uint2 bb = *(const uint2*)(bp + tt*256);
        s[0] += b2f((u16)(bb.x & 0xffffu)); s[1] += b2f((u16)(bb.x >> 16));
        s[2] += b2f((u16)(bb.y & 0xffffu)); s[3] += b2f((u16)(bb.y >> 16));
      } else {
        const int off = tt*16 + hi*4;
        int4 s4 = *(const int4*)(sp + crow + off);
        int4 t4 = *(const int4*)(spT + crow + off);
        float4 a4 = *(const float4*)(atb + crow + off);
        s[0] += a4.x + spc[s4.x] + sprc[t4.x];
        s[1] += a4.y + spc[s4.y] + sprc[t4.y];
        s[2] += a4.z + spc[s4.z] + sprc[t4.z];
        s[3] += a4.w + spc[s4.w] + sprc[t4.w];
      }
      f[tt] = s;
    }

    float mx = -3.0e38f;
    #pragma unroll
    for (int tt = 0; tt < 24; ++tt)
      mx = fmaxf(mx, fmaxf(fmaxf(f[tt][0], f[tt][1]), fmaxf(f[tt][2], f[tt][3])));
    mx = fmaxf(mx, __shfl_xor(mx, 16, 64));
    mx = fmaxf(mx, __shfl_xor(mx, 32, 64));
    float sum = 0.f;
    #pragma unroll
    for (int tt = 0; tt < 24; ++tt) {
      #pragma unroll
      for (int j = 0; j < 4; ++j) { f[tt][j] = __expf(f[tt][j] - mx); sum += f[tt][j]; }
    }
    sum += __shfl_xor(sum, 16, 64);
    sum += __shfl_xor(sum, 32, 64);
    const float inv = 1.0f / sum;

    f32x4 o0 = (f32x4){0.f,0.f,0.f,0.f}, o1 = (f32x4){0.f,0.f,0.f,0.f};
    char* prow = (char*)&Pw[wave][ql][0];
    const int swz = (ql & 3) << 4;
    #pragma unroll
    for (int c = 0; c < 12; ++c) {
      unsigned w0 = pkcvt(f[2*c][0],   f[2*c][1]);
      unsigned w1 = pkcvt(f[2*c][2],   f[2*c][3]);
      unsigned w2 = pkcvt(f[2*c+1][0], f[2*c+1][1]);
      unsigned w3 = pkcvt(f[2*c+1][2], f[2*c+1][3]);
      *(unsigned*)(prow + (((hi*8)      ) ^ swz)) = w0;
      *(unsigned*)(prow + (((hi*8) +  4) ^ swz)) = w1;
      *(unsigned*)(prow + (((hi*8) + 32) ^ swz)) = w2;
      *(unsigned*)(prow + (((hi*8) + 36) ^ swz)) = w3;
      bf16x8 a = *(const bf16x8*)(prow + ((hi*16) ^ swz));
      bf16x8 v0 = *(const bf16x8*)&Vt[ql][c*32 + hi*8];
      bf16x8 v1 = *(const bf16x8*)&Vt[16 + ql][c*32 + hi*8];
      o0 = __builtin_amdgcn_mfma_f32_16x16x32_bf16(a, v0, o0, 0, 0, 0);
      o1 = __builtin_amdgcn_mfma_f32_16x16x32_bf16(a, v1, o1, 0, 0, 0);
    }

    #pragma unroll
    for (int j = 0; j < 4; ++j) {
      float invj = __shfl(inv, hi*4 + j, 64);
      const int qg = q0 + hi*4 + j;
      u16* orow = ab + ((size_t)qg*Bb + b)*Ee + h*24;
      orow[ql] = f2b(o0[j] * invj);
      if (ql < 8) orow[16 + ql] = f2b(o1[j] * invj);
    }
    __syncthreads();   // protect Qt/Pw before restage
  }
}

// ---------------- LayerNorm over NP split-K partials (residual already folded in z0)
template<int NP>
__global__ __launch_bounds__(256) void ln_kernel(
    const float* __restrict__ delta,
    const float* __restrict__ gamma, const float* __restrict__ beta,
    float* __restrict__ xout, u16* __restrict__ xb)
{
  __shared__ float red[8];
  const int r = blockIdx.x, t = threadIdx.x;
  const size_t base = (size_t)r * Ee;
  float v[3];
  #pragma unroll
  for (int i = 0; i < 3; ++i) {
    int c = t + i*256;
    float d = 0.f;
    #pragma unroll
    for (int p = 0; p < NP; ++p) d += delta[(size_t)p*(Mm*768) + base + c];
    v[i] = d;
  }
  float s = v[0] + v[1] + v[2];
  #pragma unroll
  for (int off = 1; off < 64; off <<= 1) s += __shfl_xor(s, off, 64);
  if ((t & 63) == 0) red[t >> 6] = s;
  __syncthreads();
  const float mean = (red[0] + red[1] + red[2] + red[3]) * (1.0f / 768.0f);
  float qs = 0.f;
  #pragma unroll
  for (int i = 0; i < 3; ++i) { float d = v[i] - mean; qs += d * d; }
  #pragma unroll
  for (int off = 1; off < 64; off <<= 1) qs += __shfl_xor(qs, off, 64);
  if ((t & 63) == 0) red[4 + (t >> 6)] = qs;
  __syncthreads();
  const float var = (red[4] + red[5] + red[6] + red[7]) * (1.0f / 768.0f);
  const float rstd = rsqrtf(var + 1e-5f);
  #pragma unroll
  for (int i = 0; i < 3; ++i) {
    int c = t + i*256;
    float o = (v[i] - mean) * rstd * gamma[c] + beta[c];
    xout[base + c] = o;
    xb[base + c] = f2b(o);
  }
}

extern "C" void kernel_launch(void* const* d_in, const int* in_sizes, int n_in,
                              void* d_out, int out_size, void* d_ws, size_t ws_size,
                              hipStream_t stream) {
  const int*   node_type  = (const int*)d_in[0];
  const float* nif        = (const float*)d_in[1];
  const int*   in_deg     = (const int*)d_in[2];
  const int*   out_deg    = (const int*)d_in[3];
  const float* atb        = (const float*)d_in[4];
  const int*   sp         = (const int*)d_in[5];
  const float* node_emb   = (const float*)d_in[6];
  const float* ind_emb    = (const float*)d_in[7];
  const float* outd_emb   = (const float*)d_in[8];
  const float* sp_emb     = (const float*)d_in[9];
  const float* sp_emb_rev = (const float*)d_in[10];
  const float* Wq = (const float*)d_in[11]; const float* bq = (const float*)d_in[12];
  const float* Wk = (const float*)d_in[13]; const float* bk = (const float*)d_in[14];
  const float* Wv = (const float*)d_in[15]; const float* bv = (const float*)d_in[16];
  const float* Wo = (const float*)d_in[17]; const float* bo = (const float*)d_in[18];
  const float* W1 = (const float*)d_in[19]; const float* b1 = (const float*)d_in[20];
  const float* W2 = (const float*)d_in[21]; const float* b2 = (const float*)d_in[22];
  const float* ln1s = (const float*)d_in[23]; const float* ln1b = (const float*)d_in[24];
  const float* ln2s = (const float*)d_in[25]; const float* ln2b = (const float*)d_in[26];

  char* ws = (char*)d_ws;
  float* x      = (float*)(ws);                    //  4,718,592
  u16*   xb     = (u16*)(ws +  4718592);           //  2,359,296
  u16*   qkvb16 = (u16*)(ws +  7077888);           //  7,077,888
  u16*   abuf   = (u16*)(ws + 14155776);           //  2,359,296
  u16*   hb     = (u16*)(ws + 16515072);           //  9,437,184
  float* obufP  = (float*)(ws + 25952256);         // 18,874,368 (room for partials)
  int*   spTb   = (int*)(ws + 44826624);           //  2,359,296
  u16*   biasb  = (u16*)(ws + 47185920);           // 37,748,736 -> 84,934,656
  const bool useBias = ws_size >= 99090432ull;
  const bool allW    = ws_size >= 254803968ull;
  u16* wTall = (u16*)(ws + (useBias ? 84934656 : 47185920));
  const unsigned LSLOT = 7077888u;   // u16 elements per layer slot

  embed_kernel<<<Mm, 256, 0, stream>>>(node_type, nif, in_deg, out_deg,
                                       node_emb, ind_emb, outd_emb, x, xb);
  spT_kernel<<<dim3(12, 12, 4), dim3(32, 8), 0, stream>>>(sp, spTb);
  if (useBias)
    bias_pre_kernel<<<dim3(24, 32, 4), 256, 0, stream>>>(atb, sp, spTb, sp_emb, sp_emb_rev, biasb);
  if (allW)
    wconv_kernel<<<dim3(432, 12), 256, 0, stream>>>(Wq, Wk, Wv, Wo, W1, W2,
                                                    0, wTall, LSLOT);

  const float scaleQ = 0.2041241452319315f;  // 24^-0.5

  for (int l = 0; l < Ll; ++l) {
    const float *bql = bq + (size_t)l*Ee, *bkl = bk + (size_t)l*Ee, *bvl = bv + (size_t)l*Ee;
    const float *bol = bo + (size_t)l*Ee;
    const float *b1l = b1 + (size_t)l*Ff, *b2l = b2 + (size_t)l*Ee;

    if (!allW)
      wconv_kernel<<<dim3(432, 1), 256, 0, stream>>>(Wq, Wk, Wv, Wo, W1, W2,
                                                     l, wTall, 0u);
    u16* slot = wTall + (size_t)(allW ? l : 0) * LSLOT;
    const u16* qkvT = slot;
    const u16* woT  = slot + 1769472;
    const u16* w1T  = slot + 2359296;
    const u16* w2T  = slot + 4718592;

    // QKV: [1536,768] @ k8-wT -> bf16 [1536][2304]
    gemm3_kernel<0><<<dim3(12, 36), 256, 0, stream>>>(xb, qkvT, bql, bkl, bvl, x,
                                                      768, 6144, 768, scaleQ, nullptr, qkvb16);
    if (useBias)
      attn2_kernel<1><<<384, 256, 0, stream>>>(qkvb16, biasb, atb, sp, spTb,
                                               sp_emb, sp_emb_rev, abuf);
    else
      attn2_kernel<0><<<384, 256, 0, stream>>>(qkvb16, nullptr, atb, sp, spTb,
                                               sp_emb, sp_emb_rev, abuf);
    // O-proj: split-K 2, z0 adds bias + residual x
    gemm3_kernel<1><<<dim3(12, 12, 2), 256, 0, stream>>>(abuf, woT, bol, bol, bol, x,
                                                         768, 6144, 384, 1.0f, obufP, nullptr);
    ln_kernel<2><<<Mm, 256, 0, stream>>>(obufP, ln1s + (size_t)l*Ee, ln1b + (size_t)l*Ee, x, xb);
    // FFN1 + gelu -> bf16 hidden
    gemm3_kernel<2><<<dim3(12, 48), 256, 0, stream>>>(xb, w1T, b1l, b1l, b1l, x,
                                                      768, 24576, 768, 1.0f, nullptr, hb);
    // FFN2: split-K 2, z0 adds bias + residual x (post-LN1)
    gemm3_kernel<1><<<dim3(12, 12, 2), 256, 0, stream>>>(hb, w2T, b2l, b2l, b2l, x,
                                                         3072, 6144, 1536, 1.0f, obufP, nullptr);
    float* xdst = (l == Ll - 1) ? (float*)d_out : x;
    ln_kernel<2><<<Mm, 256, 0, stream>>>(obufP, ln2s + (size_t)l*Ee, ln2b + (size_t)l*Ee, xdst, xb);
  }
}

// Round 8
// 1478.248 us; speedup vs baseline: 1.0765x; 1.0765x over previous
//
#include <hip/hip_runtime.h>
#include <hip/hip_bf16.h>

#define Bb 4
#define Nn 384
#define Ee 768
#define Hh 32
#define Ff 3072
#define Ll 12
#define Ss 512
#define Mm (Nn*Bb)   // 1536 tokens

typedef __attribute__((ext_vector_type(8))) short bf16x8;
typedef __attribute__((ext_vector_type(4))) float f32x4;
typedef unsigned short u16;

__device__ __forceinline__ u16 f2b(float f) {
  union { float f; unsigned int i; } c; c.f = f;
  unsigned int x = c.i;
  return (u16)((x + 0x7fffu + ((x >> 16) & 1u)) >> 16); // RNE
}
__device__ __forceinline__ float b2f(u16 u) {
  union { unsigned int i; float f; } c; c.i = ((unsigned int)u) << 16; return c.f;
}
__device__ __forceinline__ unsigned pkcvt(float lo, float hi) {
  unsigned r;
  asm("v_cvt_pk_bf16_f32 %0, %1, %2" : "=v"(r) : "v"(lo), "v"(hi));
  return r;
}
__device__ __forceinline__ void gload_lds16(const void* g, void* l) {
  __builtin_amdgcn_global_load_lds((__attribute__((address_space(1))) void*)(g),
                                   (__attribute__((address_space(3))) void*)(l), 16, 0, 0);
}

// ---------------- embedding
__global__ __launch_bounds__(256) void embed_kernel(
    const int* __restrict__ node_type, const float* __restrict__ nif,
    const int* __restrict__ in_deg, const int* __restrict__ out_deg,
    const float* __restrict__ node_emb, const float* __restrict__ ind_emb,
    const float* __restrict__ outd_emb,
    float* __restrict__ x, u16* __restrict__ xb)
{
  const int r = blockIdx.x;           // r = n*B + b
  const int n = r / Bb, b = r % Bb;
  const int nt  = node_type[b*Nn + n];
  const int idg = in_deg[b*Nn + n];
  const int odg = out_deg[b*Nn + n];
  for (int c = threadIdx.x; c < Ee; c += 256) {
    float val = node_emb[(size_t)nt*Ee + c] + ind_emb[(size_t)idg*Ee + c]
              + outd_emb[(size_t)odg*Ee + c] + nif[((size_t)b*Nn + n)*Ee + c];
    x[(size_t)r*Ee + c] = val;
    xb[(size_t)r*Ee + c] = f2b(val);
  }
}

// ---------------- spatial_pos transpose
__global__ void spT_kernel(const int* __restrict__ sp, int* __restrict__ spT)
{
  __shared__ int tile[32][33];
  const int b = blockIdx.z;
  const int n0 = blockIdx.y * 32, m0 = blockIdx.x * 32;
  const int tx = threadIdx.x, ty = threadIdx.y;
  for (int i = ty; i < 32; i += 8)
    tile[i][tx] = sp[((size_t)b*Nn + n0 + i)*Nn + m0 + tx];
  __syncthreads();
  for (int i = ty; i < 32; i += 8)
    spT[((size_t)b*Nn + m0 + i)*Nn + n0 + tx] = tile[tx][i];
}

// ---------------- bias precompute into MFMA-fragment chunk layout (coalesced)
// element (q = bx*16 + qi, m = tt*16 + hi*4 + j) at
//   biasb[((b*H+h)*24 + bx)*24*256 + tt*256 + hi*64 + qi*4 + j]
__global__ __launch_bounds__(256) void bias_pre_kernel(
    const float* __restrict__ atb, const int* __restrict__ sp, const int* __restrict__ spT,
    const float* __restrict__ sp_emb, const float* __restrict__ sp_emb_rev,
    u16* __restrict__ biasb)
{
  __shared__ float spc[512], sprc[512];
  const int bx = blockIdx.x, h = blockIdx.y, b = blockIdx.z;
  const int t = threadIdx.x;
  for (int i = t; i < 512; i += 256) {
    spc[i]  = sp_emb[(size_t)i*Hh + h];
    sprc[i] = sp_emb_rev[(size_t)i*Hh + h];
  }
  __syncthreads();
  const int qi = t >> 4;                 // 0..15
  const int ml = (t & 15) << 2;          // m within 64-group, multiple of 4
  const size_t rowb = ((size_t)b*Nn + bx*16 + qi)*Nn;
  u16* outb = biasb + ((size_t)(b*Hh + h)*24 + bx)*24*256;
  #pragma unroll
  for (int mg = 0; mg < 6; ++mg) {
    const int m = mg*64 + ml;
    float4 a4 = *(const float4*)(atb + rowb + m);
    int4  s4 = *(const int4*)(sp  + rowb + m);
    int4  t4 = *(const int4*)(spT + rowb + m);
    const int tt = m >> 4, hi = (m >> 2) & 3;
    uint2 u;
    u.x = pkcvt(a4.x + spc[s4.x] + sprc[t4.x], a4.y + spc[s4.y] + sprc[t4.y]);
    u.y = pkcvt(a4.z + spc[s4.z] + sprc[t4.z], a4.w + spc[s4.w] + sprc[t4.w]);
    *(uint2*)(outb + tt*256 + hi*64 + qi*4) = u;
  }
}

// ---------------- weight convert to k8-interleaved layout: wT[kb][n][8] bf16
// depth-3 pipeline, 16 tiles/block: 2 tiles always in flight per wave.
__device__ __forceinline__ void wc3_resolve(int tid, int layer,
    const float* Wq, const float* Wk, const float* Wv, const float* Wo,
    const float* W1, const float* W2, u16* slot,
    const float*& src, u16*& dst, int& Ns, int& kb, int& nc)
{
  if (tid < 1152)      { int seg = tid/288; int r = tid - seg*288;
                         src = (seg==0?Wq:(seg==1?Wk:(seg==2?Wv:Wo))) + (size_t)layer*Ee*Ee;
                         dst = slot + (size_t)(seg<3 ? seg*589824 : 1769472);
                         Ns = 768; kb = r/3; nc = r%3; }
  else if (tid < 2304) { int r = tid-1152; src = W1 + (size_t)layer*Ee*Ff;
                         dst = slot + 2359296; Ns = 3072; kb = r/12; nc = r%12; }
  else                 { int r = tid-2304; src = W2 + (size_t)layer*Ff*Ee;
                         dst = slot + 4718592; Ns = 768;  kb = r/3;  nc = r%3; }
}

__global__ __launch_bounds__(256) void wconv_kernel(
    const float* __restrict__ Wq, const float* __restrict__ Wk, const float* __restrict__ Wv,
    const float* __restrict__ Wo, const float* __restrict__ W1, const float* __restrict__ W2,
    int layer0, u16* __restrict__ wTall, unsigned slotStride)
{
  __shared__ __align__(16) float buf[3][2048];     // 3 x 8KB (8 rows x 256 cols)
  const int t = threadIdx.x;
  const int layer = layer0 + blockIdx.y;
  u16* slot = wTall + (size_t)blockIdx.y * slotStride;
  const int tid0 = blockIdx.x * 16;
  const int lrow = t >> 6, lcol = (t & 63) << 2;   // per-wave row, 1KB contiguous

  {
    const float* s_; u16* d_; int Ns_, kb_, nc_;
    #pragma unroll
    for (int p = 0; p < 2; ++p) {
      wc3_resolve(tid0 + p, layer, Wq, Wk, Wv, Wo, W1, W2, slot, s_, d_, Ns_, kb_, nc_);
      gload_lds16(s_ + (size_t)(kb_*8 + lrow)*Ns_ + nc_*256 + lcol,
                  (char*)&buf[0][0] + p*8192 + t*16);
      gload_lds16(s_ + (size_t)(kb_*8 + 4 + lrow)*Ns_ + nc_*256 + lcol,
                  (char*)&buf[0][0] + p*8192 + 4096 + t*16);
    }
  }
  int cur = 0;
  for (int it = 0; it < 16; ++it) {
    if (it + 2 < 16) {
      const float* s_; u16* d_; int Ns_, kb_, nc_;
      wc3_resolve(tid0 + it + 2, layer, Wq, Wk, Wv, Wo, W1, W2, slot, s_, d_, Ns_, kb_, nc_);
      char* bb = (char*)&buf[0][0] + (cur == 0 ? 2 : cur - 1) * 8192;   // (cur+2)%3
      gload_lds16(s_ + (size_t)(kb_*8 + lrow)*Ns_ + nc_*256 + lcol, bb + t*16);
      gload_lds16(s_ + (size_t)(kb_*8 + 4 + lrow)*Ns_ + nc_*256 + lcol, bb + 4096 + t*16);
      asm volatile("s_waitcnt vmcnt(4)" ::: "memory");   // tile it landed; it+1,it+2 in flight
    } else if (it + 2 == 16) {
      asm volatile("s_waitcnt vmcnt(2)" ::: "memory");
    } else {
      asm volatile("s_waitcnt vmcnt(0)" ::: "memory");
    }
    __builtin_amdgcn_s_barrier();
    const float* s_; u16* d_; int Ns_, kb_, nc_;
    wc3_resolve(tid0 + it, layer, Wq, Wk, Wv, Wo, W1, W2, slot, s_, d_, Ns_, kb_, nc_);
    const float* bc = &buf[cur][0];
    uint4 u;
    u.x = pkcvt(bc[0*256 + t], bc[1*256 + t]);
    u.y = pkcvt(bc[2*256 + t], bc[3*256 + t]);
    u.z = pkcvt(bc[4*256 + t], bc[5*256 + t]);
    u.w = pkcvt(bc[6*256 + t], bc[7*256 + t]);
    *(uint4*)(d_ + (size_t)kb_*Ns_*8 + (size_t)(nc_*256 + t)*8) = u;
    __builtin_amdgcn_s_barrier();            // protect buf[cur] before re-staging
    cur = (cur == 2) ? 0 : cur + 1;
  }
}

// ---------------- 128x64-tile GEMM, BK=64, counted-vmcnt 2-barrier pipeline, XCD-swizzled
// A: [M][K] bf16 linear rows + XOR slot swizzle (rule #21).
// B: k8-interleaved wT[kb][n][8] — staging contiguous 1KB/wave-inst, frag = 1 b128.
// EPI 0: qkv fused bias (Q scaled) -> bf16 out ld 2304
// EPI 1: f32 partial out ld 768 (z==0 adds bias + residual)
// EPI 2: gelu -> bf16 out ld 3072
template<int EPI>
__global__ __launch_bounds__(256) void gemm3_kernel(
    const u16* __restrict__ A, const u16* __restrict__ Bw,
    const float* __restrict__ b0, const float* __restrict__ b1, const float* __restrict__ b2,
    const float* __restrict__ resid,
    int Kfull, int Ns8, int Kc, float scaleQ,
    float* __restrict__ outF, u16* __restrict__ outB)
{
  __shared__ __align__(16) u16 As[2][128][64];
  __shared__ __align__(16) u16 Bs[2][4096];
  const int t = threadIdx.x, lane = t & 63, wave = t >> 6;
  int bx = blockIdx.x, by = blockIdx.y;
  { // XCD swizzle (xy grid always divisible by 8)
    const int gx = gridDim.x;
    const int nwg = gx * gridDim.y;
    const int bid = bx + gx * by;
    const int cpx = nwg >> 3;
    const int s = (bid & 7) * cpx + (bid >> 3);
    bx = s % gx; by = s / gx;
  }
  const int m0 = bx * 128, n0 = by * 64;
  const int k0 = blockIdx.z * Kc;
  const int wm = wave >> 1, wn = wave & 1;
  const int ql = lane & 15, hi = lane >> 4;
  const int nk = Kc >> 6;
  // EPI0 segment (tiles never straddle 768-col segments)
  int n0loc = n0; size_t bsegoff = 0;
  if (EPI == 0) { const int seg = n0 / 768; n0loc = n0 - seg*768; bsegoff = (size_t)seg*589824; }
  // A staging map
  const int sr = t >> 3;
  const int sslot = (t & 7) ^ (sr & 7);
  const size_t aoff = (size_t)(m0 + sr)*Kfull + k0 + (sslot << 3);
  const size_t rstep = (size_t)32 * Kfull;
  // B staging map: 2 chunks per thread, XOR'd source n
  const int c0kb = t >> 6,         c0j = t & 63;
  const int c1kb = (t + 256) >> 6, c1j = t & 63;
  const size_t bo0 = bsegoff + (size_t)c0kb*Ns8 + (size_t)(n0loc + (c0j ^ (c0kb & 7)))*8;
  const size_t bo1 = bsegoff + (size_t)c1kb*Ns8 + (size_t)(n0loc + (c1j ^ (c1kb & 7)))*8;
  const int kb0base = k0 >> 3;

  // fragment LDS byte offsets
  int aro[4][2], bro[2][2];
  #pragma unroll
  for (int ks = 0; ks < 2; ++ks) {
    const int kbA = (((ks<<2) + hi) ^ (ql & 7)) << 4;
    #pragma unroll
    for (int f = 0; f < 4; ++f) aro[f][ks] = (wm*64 + f*16 + ql)*128 + kbA;
    #pragma unroll
    for (int f = 0; f < 2; ++f) {
      const int kbB = (ks<<2) + hi;
      bro[f][ks] = ((kbB*64) + ((wn*32 + f*16 + ql) ^ kbB)) << 4;
    }
  }

  f32x4 acc[4][2];
  #pragma unroll
  for (int a = 0; a < 4; ++a)
    #pragma unroll
    for (int c = 0; c < 2; ++c) acc[a][c] = (f32x4){0.f,0.f,0.f,0.f};

  // prologue: issue tile 0
  #pragma unroll
  for (int i = 0; i < 4; ++i)
    gload_lds16(A + aoff + i*rstep, (char*)&As[0][0][0] + i*4096 + t*16);
  gload_lds16(Bw + (size_t)kb0base*Ns8 + bo0, (char*)&Bs[0][0] + t*16);
  gload_lds16(Bw + (size_t)kb0base*Ns8 + bo1, (char*)&Bs[0][0] + 4096 + t*16);

  for (int kt = 0; kt < nk; ++kt) {
    const int cur = kt & 1, nxt = cur ^ 1;
    const bool pre = (kt + 1 < nk);
    if (pre) {
      const size_t kk = (size_t)(kt + 1) << 6;
      #pragma unroll
      for (int i = 0; i < 4; ++i)
        gload_lds16(A + aoff + kk + i*rstep, (char*)&As[nxt][0][0] + i*4096 + t*16);
      const size_t kbrow = (size_t)(kb0base + (kt + 1)*8)*Ns8;
      gload_lds16(Bw + kbrow + bo0, (char*)&Bs[nxt][0] + t*16);
      gload_lds16(Bw + kbrow + bo1, (char*)&Bs[nxt][0] + 4096 + t*16);
      asm volatile("s_waitcnt vmcnt(6)" ::: "memory");   // tile kt landed; kt+1 in flight
    } else {
      asm volatile("s_waitcnt vmcnt(0)" ::: "memory");
    }
    __builtin_amdgcn_s_barrier();            // B1
    __builtin_amdgcn_sched_barrier(0);

    const char* aBase = (const char*)&As[cur][0][0];
    const char* bBase = (const char*)&Bs[cur][0];
    bf16x8 af[4][2], bf[2][2];
    #pragma unroll
    for (int f = 0; f < 4; ++f)
      #pragma unroll
      for (int ks = 0; ks < 2; ++ks)
        af[f][ks] = *(const bf16x8*)(aBase + aro[f][ks]);
    #pragma unroll
    for (int f = 0; f < 2; ++f)
      #pragma unroll
      for (int ks = 0; ks < 2; ++ks)
        bf[f][ks] = *(const bf16x8*)(bBase + bro[f][ks]);
    #pragma unroll
    for (int ks = 0; ks < 2; ++ks)
      #pragma unroll
      for (int fm = 0; fm < 4; ++fm)
        #pragma unroll
        for (int fn = 0; fn < 2; ++fn)
          acc[fm][fn] = __builtin_amdgcn_mfma_f32_16x16x32_bf16(af[fm][ks], bf[fn][ks], acc[fm][fn], 0, 0, 0);
    if (pre) {
      __builtin_amdgcn_sched_barrier(0);
      __builtin_amdgcn_s_barrier();          // B2: cur reads drained before overwrite
    }
  }

  #pragma unroll
  for (int fm = 0; fm < 4; ++fm) {
    const int rowb = m0 + wm*64 + fm*16 + hi*4;
    #pragma unroll
    for (int fn = 0; fn < 2; ++fn) {
      const int gcol = n0 + wn*32 + fn*16 + ql;
      float bv = 0.f, scale = 1.0f;
      if (EPI == 0) {
        const int seg = gcol / 768;
        const int cw = gcol - seg*768;
        bv = (seg == 0) ? b0[cw] : ((seg == 1) ? b1[cw] : b2[cw]);
        if (seg == 0) scale = scaleQ;
      } else if (EPI == 1) {
        bv = (blockIdx.z == 0) ? b0[gcol] : 0.0f;
      } else {
        bv = b0[gcol];
      }
      f32x4 v = acc[fm][fn];
      #pragma unroll
      for (int j = 0; j < 4; ++j) {
        float val = (v[j] + bv) * scale;
        if (EPI == 0) {
          outB[(size_t)(rowb + j) * 2304 + gcol] = f2b(val);
        } else if (EPI == 1) {
          if (blockIdx.z == 0) val += resid[(size_t)(rowb + j) * 768 + gcol];
          outF[(size_t)blockIdx.z * (Mm*768) + (size_t)(rowb + j) * 768 + gcol] = val;
        } else {
          float arg = 0.7978845608028654f * (val + 0.044715f * val * val * val);
          float e = __expf(2.0f * arg);
          float g = 0.5f * val * (2.0f - 2.0f / (e + 1.0f));
          outB[(size_t)(rowb + j) * 3072 + gcol] = f2b(g);
        }
      }
    }
  }
}

// ---------------- MFMA attention: block = (b, h, pair of 64-q-row tiles)
template<int PREBIAS>
__global__ __launch_bounds__(256) void attn2_kernel(
    const u16* __restrict__ qkv,         // [1536][2304] bf16 q|k|v (q pre-scaled)
    const u16* __restrict__ biasb,       // chunk layout (PREBIAS=1)
    const float* __restrict__ atb, const int* __restrict__ sp, const int* __restrict__ spT,
    const float* __restrict__ sp_emb, const float* __restrict__ sp_emb_rev,
    u16* __restrict__ ab)                // [1536][768] bf16
{
  __shared__ __align__(16) u16 Kt[384][32];   // [m][d(24)+pad]
  __shared__ __align__(16) u16 Vt[32][392];   // [d(24)+pad][m] transposed
  __shared__ __align__(16) u16 Qt[64][32];
  __shared__ __align__(16) u16 Pw[4][16][32]; // per-wave P chunk
  __shared__ float spc[512], sprc[512];
  const int bid = blockIdx.x;
  const int pair = bid % 3;
  const int h = (bid / 3) % Hh;
  const int b = bid / (3 * Hh);
  const int t = threadIdx.x, lane = t & 63, wave = t >> 6;
  const int ql = lane & 15, hi = lane >> 4;

  for (int idx = t; idx < 384*6; idx += 256) {
    const int m = idx / 6, c = idx - m*6;
    const u16* base = qkv + ((size_t)m*Bb + b)*2304 + h*24 + c*4;
    uint2 kk = *(const uint2*)(base + 768);
    uint2 vv = *(const uint2*)(base + 1536);
    *(uint2*)&Kt[m][c*4] = kk;
    Vt[c*4+0][m] = (u16)(vv.x & 0xffffu); Vt[c*4+1][m] = (u16)(vv.x >> 16);
    Vt[c*4+2][m] = (u16)(vv.y & 0xffffu); Vt[c*4+3][m] = (u16)(vv.y >> 16);
  }
  for (int idx = t; idx < 384*2; idx += 256)           // K d-pad
    *(uint2*)&Kt[idx>>1][24 + (idx&1)*4] = make_uint2(0u, 0u);
  for (int idx = t; idx < 8*196; idx += 256)           // V^T d-pad rows
    *(unsigned*)((char*)&Vt[24][0] + idx*4) = 0u;
  for (int idx = t; idx < 64*2; idx += 256)            // Q d-pad
    *(uint2*)&Qt[idx>>1][24 + (idx&1)*4] = make_uint2(0u, 0u);
  if (!PREBIAS) {
    for (int i = t; i < 512; i += 256) {
      spc[i]  = sp_emb[(size_t)i*Hh + h];
      sprc[i] = sp_emb_rev[(size_t)i*Hh + h];
    }
  }

  for (int qi = 0; qi < 2; ++qi) {
    const int ntile = pair*2 + qi;
    for (int idx = t; idx < 64*6; idx += 256) {
      const int qr = idx / 6, c = idx - qr*6;
      const u16* base = qkv + ((size_t)(ntile*64 + qr)*Bb + b)*2304 + h*24 + c*4;
      *(uint2*)&Qt[qr][c*4] = *(const uint2*)base;
    }
    __syncthreads();   // covers K/V staging (iter 0) and Qt restage

    const int q0 = ntile*64 + wave*16;
    const int q = q0 + ql;
    const bf16x8 qf = *(const bf16x8*)&Qt[wave*16 + ql][hi*8];

    f32x4 f[24];
    const u16* bp = biasb + (((size_t)(b*Hh + h)*24 + ntile*4 + wave)*24)*256 + lane*4;
    const size_t crow = ((size_t)b*Nn + q)*Nn;
    #pragma unroll
    for (int tt = 0; tt < 24; ++tt) {
      bf16x8 kf = *(const bf16x8*)&Kt[tt*16 + ql][hi*8];
      f32x4 z = (f32x4){0.f,0.f,0.f,0.f};
      f32x4 s = __builtin_amdgcn_mfma_f32_16x16x32_bf16(kf, qf, z, 0, 0, 0);
      if (PREBIAS) {
        uint2 bb = *(const uint2*)(bp + tt*256);
        s[0] += b2f((u16)(bb.x & 0xffffu)); s[1] += b2f((u16)(bb.x >> 16));
        s[2] += b2f((u16)(bb.y & 0xffffu)); s[3] += b2f((u16)(bb.y >> 16));
      } else {
        const int off = tt*16 + hi*4;
        int4 s4 = *(const int4*)(sp + crow + off);
        int4 t4 = *(const int4*)(spT + crow + off);
        float4 a4 = *(const float4*)(atb + crow + off);
        s[0] += a4.x + spc[s4.x] + sprc[t4.x];
        s[1] += a4.y + spc[s4.y] + sprc[t4.y];
        s[2] += a4.z + spc[s4.z] + sprc[t4.z];
        s[3] += a4.w + spc[s4.w] + sprc[t4.w];
      }
      f[tt] = s;
    }

    float mx = -3.0e38f;
    #pragma unroll
    for (int tt = 0; tt < 24; ++tt)
      mx = fmaxf(mx, fmaxf(fmaxf(f[tt][0], f[tt][1]), fmaxf(f[tt][2], f[tt][3])));
    mx = fmaxf(mx, __shfl_xor(mx, 16, 64));
    mx = fmaxf(mx, __shfl_xor(mx, 32, 64));
    float sum = 0.f;
    #pragma unroll
    for (int tt = 0; tt < 24; ++tt) {
      #pragma unroll
      for (int j = 0; j < 4; ++j) { f[tt][j] = __expf(f[tt][j] - mx); sum += f[tt][j]; }
    }
    sum += __shfl_xor(sum, 16, 64);
    sum += __shfl_xor(sum, 32, 64);
    const float inv = 1.0f / sum;

    f32x4 o0 = (f32x4){0.f,0.f,0.f,0.f}, o1 = (f32x4){0.f,0.f,0.f,0.f};
    char* prow = (char*)&Pw[wave][ql][0];
    const int swz = (ql & 3) << 4;
    #pragma unroll
    for (int c = 0; c < 12; ++c) {
      unsigned w0 = pkcvt(f[2*c][0],   f[2*c][1]);
      unsigned w1 = pkcvt(f[2*c][2],   f[2*c][3]);
      unsigned w2 = pkcvt(f[2*c+1][0], f[2*c+1][1]);
      unsigned w3 = pkcvt(f[2*c+1][2], f[2*c+1][3]);
      *(unsigned*)(prow + (((hi*8)      ) ^ swz)) = w0;
      *(unsigned*)(prow + (((hi*8) +  4) ^ swz)) = w1;
      *(unsigned*)(prow + (((hi*8) + 32) ^ swz)) = w2;
      *(unsigned*)(prow + (((hi*8) + 36) ^ swz)) = w3;
      bf16x8 a = *(const bf16x8*)(prow + ((hi*16) ^ swz));
      bf16x8 v0 = *(const bf16x8*)&Vt[ql][c*32 + hi*8];
      bf16x8 v1 = *(const bf16x8*)&Vt[16 + ql][c*32 + hi*8];
      o0 = __builtin_amdgcn_mfma_f32_16x16x32_bf16(a, v0, o0, 0, 0, 0);
      o1 = __builtin_amdgcn_mfma_f32_16x16x32_bf16(a, v1, o1, 0, 0, 0);
    }

    #pragma unroll
    for (int j = 0; j < 4; ++j) {
      float invj = __shfl(inv, hi*4 + j, 64);
      const int qg = q0 + hi*4 + j;
      u16* orow = ab + ((size_t)qg*Bb + b)*Ee + h*24;
      orow[ql] = f2b(o0[j] * invj);
      if (ql < 8) orow[16 + ql] = f2b(o1[j] * invj);
    }
    __syncthreads();   // protect Qt/Pw before restage
  }
}

// ---------------- LayerNorm over NP split-K partials (residual already folded in z0)
template<int NP>
__global__ __launch_bounds__(256) void ln_kernel(
    const float* __restrict__ delta,
    const float* __restrict__ gamma, const float* __restrict__ beta,
    float* __restrict__ xout, u16* __restrict__ xb)
{
  __shared__ float red[8];
  const int r = blockIdx.x, t = threadIdx.x;
  const size_t base = (size_t)r * Ee;
  float v[3];
  #pragma unroll
  for (int i = 0; i < 3; ++i) {
    int c = t + i*256;
    float d = 0.f;
    #pragma unroll
    for (int p = 0; p < NP; ++p) d += delta[(size_t)p*(Mm*768) + base + c];
    v[i] = d;
  }
  float s = v[0] + v[1] + v[2];
  #pragma unroll
  for (int off = 1; off < 64; off <<= 1) s += __shfl_xor(s, off, 64);
  if ((t & 63) == 0) red[t >> 6] = s;
  __syncthreads();
  const float mean = (red[0] + red[1] + red[2] + red[3]) * (1.0f / 768.0f);
  float qs = 0.f;
  #pragma unroll
  for (int i = 0; i < 3; ++i) { float d = v[i] - mean; qs += d * d; }
  #pragma unroll
  for (int off = 1; off < 64; off <<= 1) qs += __shfl_xor(qs, off, 64);
  if ((t & 63) == 0) red[4 + (t >> 6)] = qs;
  __syncthreads();
  const float var = (red[4] + red[5] + red[6] + red[7]) * (1.0f / 768.0f);
  const float rstd = rsqrtf(var + 1e-5f);
  #pragma unroll
  for (int i = 0; i < 3; ++i) {
    int c = t + i*256;
    float o = (v[i] - mean) * rstd * gamma[c] + beta[c];
    xout[base + c] = o;
    xb[base + c] = f2b(o);
  }
}

extern "C" void kernel_launch(void* const* d_in, const int* in_sizes, int n_in,
                              void* d_out, int out_size, void* d_ws, size_t ws_size,
                              hipStream_t stream) {
  const int*   node_type  = (const int*)d_in[0];
  const float* nif        = (const float*)d_in[1];
  const int*   in_deg     = (const int*)d_in[2];
  const int*   out_deg    = (const int*)d_in[3];
  const float* atb        = (const float*)d_in[4];
  const int*   sp         = (const int*)d_in[5];
  const float* node_emb   = (const float*)d_in[6];
  const float* ind_emb    = (const float*)d_in[7];
  const float* outd_emb   = (const float*)d_in[8];
  const float* sp_emb     = (const float*)d_in[9];
  const float* sp_emb_rev = (const float*)d_in[10];
  const float* Wq = (const float*)d_in[11]; const float* bq = (const float*)d_in[12];
  const float* Wk = (const float*)d_in[13]; const float* bk = (const float*)d_in[14];
  const float* Wv = (const float*)d_in[15]; const float* bv = (const float*)d_in[16];
  const float* Wo = (const float*)d_in[17]; const float* bo = (const float*)d_in[18];
  const float* W1 = (const float*)d_in[19]; const float* b1 = (const float*)d_in[20];
  const float* W2 = (const float*)d_in[21]; const float* b2 = (const float*)d_in[22];
  const float* ln1s = (const float*)d_in[23]; const float* ln1b = (const float*)d_in[24];
  const float* ln2s = (const float*)d_in[25]; const float* ln2b = (const float*)d_in[26];

  char* ws = (char*)d_ws;
  float* x      = (float*)(ws);                    //  4,718,592
  u16*   xb     = (u16*)(ws +  4718592);           //  2,359,296
  u16*   qkvb16 = (u16*)(ws +  7077888);           //  7,077,888
  u16*   abuf   = (u16*)(ws + 14155776);           //  2,359,296
  u16*   hb     = (u16*)(ws + 16515072);           //  9,437,184
  float* obufP  = (float*)(ws + 25952256);         // 18,874,368 (4 partials)
  int*   spTb   = (int*)(ws + 44826624);           //  2,359,296
  u16*   biasb  = (u16*)(ws + 47185920);           // 37,748,736 -> 84,934,656
  const bool useBias = ws_size >= 99090432ull;
  const bool allW    = ws_size >= 254803968ull;
  u16* wTall = (u16*)(ws + (useBias ? 84934656 : 47185920));
  const unsigned LSLOT = 7077888u;   // u16 elements per layer slot

  embed_kernel<<<Mm, 256, 0, stream>>>(node_type, nif, in_deg, out_deg,
                                       node_emb, ind_emb, outd_emb, x, xb);
  spT_kernel<<<dim3(12, 12, 4), dim3(32, 8), 0, stream>>>(sp, spTb);
  if (useBias)
    bias_pre_kernel<<<dim3(24, 32, 4), 256, 0, stream>>>(atb, sp, spTb, sp_emb, sp_emb_rev, biasb);
  if (allW)
    wconv_kernel<<<dim3(216, 12), 256, 0, stream>>>(Wq, Wk, Wv, Wo, W1, W2,
                                                    0, wTall, LSLOT);

  const float scaleQ = 0.2041241452319315f;  // 24^-0.5

  for (int l = 0; l < Ll; ++l) {
    const float *bql = bq + (size_t)l*Ee, *bkl = bk + (size_t)l*Ee, *bvl = bv + (size_t)l*Ee;
    const float *bol = bo + (size_t)l*Ee;
    const float *b1l = b1 + (size_t)l*Ff, *b2l = b2 + (size_t)l*Ee;

    if (!allW)
      wconv_kernel<<<dim3(216, 1), 256, 0, stream>>>(Wq, Wk, Wv, Wo, W1, W2,
                                                     l, wTall, 0u);
    u16* slot = wTall + (size_t)(allW ? l : 0) * LSLOT;
    const u16* qkvT = slot;
    const u16* woT  = slot + 1769472;
    const u16* w1T  = slot + 2359296;
    const u16* w2T  = slot + 4718592;

    // QKV: [1536,768] @ k8-wT -> bf16 [1536][2304]
    gemm3_kernel<0><<<dim3(12, 36), 256, 0, stream>>>(xb, qkvT, bql, bkl, bvl, x,
                                                      768, 6144, 768, scaleQ, nullptr, qkvb16);
    if (useBias)
      attn2_kernel<1><<<384, 256, 0, stream>>>(qkvb16, biasb, atb, sp, spTb,
                                               sp_emb, sp_emb_rev, abuf);
    else
      attn2_kernel<0><<<384, 256, 0, stream>>>(qkvb16, nullptr, atb, sp, spTb,
                                               sp_emb, sp_emb_rev, abuf);
    // O-proj: split-K 2, z0 adds bias + residual x
    gemm3_kernel<1><<<dim3(12, 12, 2), 256, 0, stream>>>(abuf, woT, bol, bol, bol, x,
                                                         768, 6144, 384, 1.0f, obufP, nullptr);
    ln_kernel<2><<<Mm, 256, 0, stream>>>(obufP, ln1s + (size_t)l*Ee, ln1b + (size_t)l*Ee, x, xb);
    // FFN1 + gelu -> bf16 hidden
    gemm3_kernel<2><<<dim3(12, 48), 256, 0, stream>>>(xb, w1T, b1l, b1l, b1l, x,
                                                      768, 24576, 768, 1.0f, nullptr, hb);
    // FFN2: split-K 4 (576 blocks, Kc=768), z0 adds bias + residual x (post-LN1)
    gemm3_kernel<1><<<dim3(12, 12, 4), 256, 0, stream>>>(hb, w2T, b2l, b2l, b2l, x,
                                                         3072, 6144, 768, 1.0f, obufP, nullptr);
    float* xdst = (l == Ll - 1) ? (float*)d_out : x;
    ln_kernel<4><<<Mm, 256, 0, stream>>>(obufP, ln2s + (size_t)l*Ee, ln2b + (size_t)l*Ee, xdst, xb);
  }
}

// Round 9
// 1291.042 us; speedup vs baseline: 1.2326x; 1.1450x over previous
//
#include <hip/hip_runtime.h>
#include <hip/hip_bf16.h>

#define Bb 4
#define Nn 384
#define Ee 768
#define Hh 32
#define Ff 3072
#define Ll 12
#define Ss 512
#define Mm (Nn*Bb)   // 1536 tokens

typedef __attribute__((ext_vector_type(8))) short bf16x8;
typedef __attribute__((ext_vector_type(4))) float f32x4;
typedef unsigned short u16;

__device__ __forceinline__ u16 f2b(float f) {
  union { float f; unsigned int i; } c; c.f = f;
  unsigned int x = c.i;
  return (u16)((x + 0x7fffu + ((x >> 16) & 1u)) >> 16); // RNE
}
__device__ __forceinline__ float b2f(u16 u) {
  union { unsigned int i; float f; } c; c.i = ((unsigned int)u) << 16; return c.f;
}
__device__ __forceinline__ unsigned pkcvt(float lo, float hi) {
  unsigned r;
  asm("v_cvt_pk_bf16_f32 %0, %1, %2" : "=v"(r) : "v"(lo), "v"(hi));
  return r;
}
__device__ __forceinline__ void gload_lds16(const void* g, void* l) {
  __builtin_amdgcn_global_load_lds((__attribute__((address_space(1))) void*)(g),
                                   (__attribute__((address_space(3))) void*)(l), 16, 0, 0);
}

// ---------------- embedding
__global__ __launch_bounds__(256) void embed_kernel(
    const int* __restrict__ node_type, const float* __restrict__ nif,
    const int* __restrict__ in_deg, const int* __restrict__ out_deg,
    const float* __restrict__ node_emb, const float* __restrict__ ind_emb,
    const float* __restrict__ outd_emb,
    float* __restrict__ x, u16* __restrict__ xb)
{
  const int r = blockIdx.x;           // r = n*B + b
  const int n = r / Bb, b = r % Bb;
  const int nt  = node_type[b*Nn + n];
  const int idg = in_deg[b*Nn + n];
  const int odg = out_deg[b*Nn + n];
  for (int c = threadIdx.x; c < Ee; c += 256) {
    float val = node_emb[(size_t)nt*Ee + c] + ind_emb[(size_t)idg*Ee + c]
              + outd_emb[(size_t)odg*Ee + c] + nif[((size_t)b*Nn + n)*Ee + c];
    x[(size_t)r*Ee + c] = val;
    xb[(size_t)r*Ee + c] = f2b(val);
  }
}

// ---------------- spatial_pos transpose
__global__ void spT_kernel(const int* __restrict__ sp, int* __restrict__ spT)
{
  __shared__ int tile[32][33];
  const int b = blockIdx.z;
  const int n0 = blockIdx.y * 32, m0 = blockIdx.x * 32;
  const int tx = threadIdx.x, ty = threadIdx.y;
  for (int i = ty; i < 32; i += 8)
    tile[i][tx] = sp[((size_t)b*Nn + n0 + i)*Nn + m0 + tx];
  __syncthreads();
  for (int i = ty; i < 32; i += 8)
    spT[((size_t)b*Nn + m0 + i)*Nn + n0 + tx] = tile[tx][i];
}

// ---------------- bias precompute into MFMA-fragment chunk layout (coalesced)
__global__ __launch_bounds__(256) void bias_pre_kernel(
    const float* __restrict__ atb, const int* __restrict__ sp, const int* __restrict__ spT,
    const float* __restrict__ sp_emb, const float* __restrict__ sp_emb_rev,
    u16* __restrict__ biasb)
{
  __shared__ float spc[512], sprc[512];
  const int bx = blockIdx.x, h = blockIdx.y, b = blockIdx.z;
  const int t = threadIdx.x;
  for (int i = t; i < 512; i += 256) {
    spc[i]  = sp_emb[(size_t)i*Hh + h];
    sprc[i] = sp_emb_rev[(size_t)i*Hh + h];
  }
  __syncthreads();
  const int qi = t >> 4;                 // 0..15
  const int ml = (t & 15) << 2;          // m within 64-group, multiple of 4
  const size_t rowb = ((size_t)b*Nn + bx*16 + qi)*Nn;
  u16* outb = biasb + ((size_t)(b*Hh + h)*24 + bx)*24*256;
  #pragma unroll
  for (int mg = 0; mg < 6; ++mg) {
    const int m = mg*64 + ml;
    float4 a4 = *(const float4*)(atb + rowb + m);
    int4  s4 = *(const int4*)(sp  + rowb + m);
    int4  t4 = *(const int4*)(spT + rowb + m);
    const int tt = m >> 4, hi = (m >> 2) & 3;
    uint2 u;
    u.x = pkcvt(a4.x + spc[s4.x] + sprc[t4.x], a4.y + spc[s4.y] + sprc[t4.y]);
    u.y = pkcvt(a4.z + spc[s4.z] + sprc[t4.z], a4.w + spc[s4.w] + sprc[t4.w]);
    *(uint2*)(outb + tt*256 + hi*64 + qi*4) = u;
  }
}

// ---------------- weight transpose+convert: src f32 [Ks][Ns] -> dst bf16 [Ns][Ks]
// LDS stride 65 floats: both phases uniform 2-way (= conflict-free, m136)
__global__ __launch_bounds__(256) void wconv_kernel(
    const float* __restrict__ Wq, const float* __restrict__ Wk, const float* __restrict__ Wv,
    const float* __restrict__ Wo, const float* __restrict__ W1, const float* __restrict__ W2,
    int layer, u16* __restrict__ slot)
{
  __shared__ float tile[64][65];
  int tid = blockIdx.x;
  const float* src; u16* dst; int Ns, Ks;
  if (tid < 432)       { int seg = tid / 144; tid -= seg*144;
                         src = (seg==0?Wq:(seg==1?Wk:Wv)) + (size_t)layer*Ee*Ee;
                         dst = slot + (size_t)seg*589824; Ns = 768; Ks = 768; }
  else if (tid < 576)  { tid -= 432; src = Wo + (size_t)layer*Ee*Ee; dst = slot + 1769472; Ns = 768;  Ks = 768; }
  else if (tid < 1152) { tid -= 576; src = W1 + (size_t)layer*Ee*Ff; dst = slot + 2359296; Ns = 3072; Ks = 768; }
  else                 { tid -= 1152; src = W2 + (size_t)layer*Ff*Ee; dst = slot + 4718592; Ns = 768; Ks = 3072; }
  const int tc = Ns >> 6;
  const int tk = tid / tc, tn = tid % tc;
  const int t = threadIdx.x;
  #pragma unroll
  for (int i = 0; i < 4; ++i) {
    const int id = t + i*256;
    const int r = id >> 4, c = (id & 15) << 2;
    float4 v = *(const float4*)(src + (size_t)(tk*64 + r)*Ns + tn*64 + c);
    tile[r][c+0] = v.x; tile[r][c+1] = v.y; tile[r][c+2] = v.z; tile[r][c+3] = v.w;
  }
  __syncthreads();
  #pragma unroll
  for (int i = 0; i < 2; ++i) {
    const int ch = t + i*256;
    const int n = ch >> 3, kc = (ch & 7) << 3;
    uint4 u;
    u.x = pkcvt(tile[kc+0][n], tile[kc+1][n]);
    u.y = pkcvt(tile[kc+2][n], tile[kc+3][n]);
    u.z = pkcvt(tile[kc+4][n], tile[kc+5][n]);
    u.w = pkcvt(tile[kc+6][n], tile[kc+7][n]);
    *(uint4*)(dst + (size_t)(tn*64 + n)*Ks + tk*64 + kc) = u;
  }
}

// ---------------- 128x64-tile GEMM, BK=64, counted-vmcnt 2-barrier pipeline, XCD-swizzled
// (the proven r5 structure). Both-sides XOR swizzle (rule #21).
// EPI 0: qkv fused bias (Q scaled) -> bf16 out ld 2304
// EPI 1: f32 partial out ld 768 (bias only on z==0)
// EPI 2: gelu -> bf16 out ld 3072
template<int EPI>
__global__ __launch_bounds__(256) void gemm3_kernel(
    const u16* __restrict__ A, const u16* __restrict__ Bw,
    const float* __restrict__ b0, const float* __restrict__ b1, const float* __restrict__ b2,
    int Kfull, int Kc, float scaleQ,
    float* __restrict__ outF, u16* __restrict__ outB)
{
  __shared__ __align__(16) u16 As[2][128][64];
  __shared__ __align__(16) u16 Bs[2][64][64];
  const int t = threadIdx.x, lane = t & 63, wave = t >> 6;
  int bx = blockIdx.x, by = blockIdx.y;
  { // XCD swizzle (xy grid always divisible by 8)
    const int gx = gridDim.x;
    const int nwg = gx * gridDim.y;
    const int bid = bx + gx * by;
    const int cpx = nwg >> 3;
    const int s = (bid & 7) * cpx + (bid >> 3);
    bx = s % gx; by = s / gx;
  }
  const int m0 = bx * 128, n0 = by * 64;
  const int k0 = blockIdx.z * Kc;
  const int wm = wave >> 1, wn = wave & 1;
  const int ql = lane & 15, hi = lane >> 4;
  const int nk = Kc >> 6;
  const int sr = t >> 3;
  const int sslot = (t & 7) ^ (sr & 7);
  const size_t aoff = (size_t)(m0 + sr)*Kfull + k0 + (sslot << 3);
  const size_t boff = (size_t)(n0 + sr)*Kfull + k0 + (sslot << 3);
  const size_t rstep = (size_t)32 * Kfull;

  int aro[4][2], bro[2][2];
  #pragma unroll
  for (int ks = 0; ks < 2; ++ks) {
    const int kb = (((ks<<2) + hi) ^ (ql & 7)) << 4;
    #pragma unroll
    for (int f = 0; f < 4; ++f) aro[f][ks] = (wm*64 + f*16 + ql)*128 + kb;
    #pragma unroll
    for (int f = 0; f < 2; ++f) bro[f][ks] = (wn*32 + f*16 + ql)*128 + kb;
  }

  f32x4 acc[4][2];
  #pragma unroll
  for (int a = 0; a < 4; ++a)
    #pragma unroll
    for (int c = 0; c < 2; ++c) acc[a][c] = (f32x4){0.f,0.f,0.f,0.f};

  #pragma unroll
  for (int i = 0; i < 4; ++i)
    gload_lds16(A + aoff + i*rstep, (char*)&As[0][0][0] + i*4096 + t*16);
  #pragma unroll
  for (int i = 0; i < 2; ++i)
    gload_lds16(Bw + boff + i*rstep, (char*)&Bs[0][0][0] + i*4096 + t*16);

  for (int kt = 0; kt < nk; ++kt) {
    const int cur = kt & 1, nxt = cur ^ 1;
    const bool pre = (kt + 1 < nk);
    if (pre) {
      const size_t kk = (size_t)(kt + 1) << 6;
      #pragma unroll
      for (int i = 0; i < 4; ++i)
        gload_lds16(A + aoff + kk + i*rstep, (char*)&As[nxt][0][0] + i*4096 + t*16);
      #pragma unroll
      for (int i = 0; i < 2; ++i)
        gload_lds16(Bw + boff + kk + i*rstep, (char*)&Bs[nxt][0][0] + i*4096 + t*16);
      asm volatile("s_waitcnt vmcnt(6)" ::: "memory");   // tile kt landed; kt+1 in flight
    } else {
      asm volatile("s_waitcnt vmcnt(0)" ::: "memory");
    }
    __builtin_amdgcn_s_barrier();            // B1
    __builtin_amdgcn_sched_barrier(0);

    const char* aBase = (const char*)&As[cur][0][0];
    const char* bBase = (const char*)&Bs[cur][0][0];
    bf16x8 af[4][2], bf[2][2];
    #pragma unroll
    for (int f = 0; f < 4; ++f)
      #pragma unroll
      for (int ks = 0; ks < 2; ++ks)
        af[f][ks] = *(const bf16x8*)(aBase + aro[f][ks]);
    #pragma unroll
    for (int f = 0; f < 2; ++f)
      #pragma unroll
      for (int ks = 0; ks < 2; ++ks)
        bf[f][ks] = *(const bf16x8*)(bBase + bro[f][ks]);
    #pragma unroll
    for (int ks = 0; ks < 2; ++ks)
      #pragma unroll
      for (int fm = 0; fm < 4; ++fm)
        #pragma unroll
        for (int fn = 0; fn < 2; ++fn)
          acc[fm][fn] = __builtin_amdgcn_mfma_f32_16x16x32_bf16(af[fm][ks], bf[fn][ks], acc[fm][fn], 0, 0, 0);
    if (pre) {
      __builtin_amdgcn_sched_barrier(0);
      __builtin_amdgcn_s_barrier();          // B2: cur reads drained before overwrite
    }
  }

  #pragma unroll
  for (int fm = 0; fm < 4; ++fm) {
    const int rowb = m0 + wm*64 + fm*16 + hi*4;
    #pragma unroll
    for (int fn = 0; fn < 2; ++fn) {
      const int gcol = n0 + wn*32 + fn*16 + ql;
      float bv, scale = 1.0f;
      if (EPI == 0) {
        const int seg = gcol / 768;
        const int cw = gcol - seg*768;
        bv = (seg == 0) ? b0[cw] : ((seg == 1) ? b1[cw] : b2[cw]);
        if (seg == 0) scale = scaleQ;
      } else if (EPI == 1) {
        bv = (blockIdx.z == 0) ? b0[gcol] : 0.0f;
      } else {
        bv = b0[gcol];
      }
      f32x4 v = acc[fm][fn];
      #pragma unroll
      for (int j = 0; j < 4; ++j) {
        float val = (v[j] + bv) * scale;
        if (EPI == 0) {
          outB[(size_t)(rowb + j) * 2304 + gcol] = f2b(val);
        } else if (EPI == 1) {
          outF[(size_t)blockIdx.z * (Mm*768) + (size_t)(rowb + j) * 768 + gcol] = val;
        } else {
          float arg = 0.7978845608028654f * (val + 0.044715f * val * val * val);
          float e = __expf(2.0f * arg);
          float g = 0.5f * val * (2.0f - 2.0f / (e + 1.0f));
          outB[(size_t)(rowb + j) * 3072 + gcol] = f2b(g);
        }
      }
    }
  }
}

// ---------------- MFMA attention: block = (b, h, pair of 64-q-row tiles)
template<int PREBIAS>
__global__ __launch_bounds__(256) void attn2_kernel(
    const u16* __restrict__ qkv,         // [1536][2304] bf16 q|k|v (q pre-scaled)
    const u16* __restrict__ biasb,       // chunk layout (PREBIAS=1)
    const float* __restrict__ atb, const int* __restrict__ sp, const int* __restrict__ spT,
    const float* __restrict__ sp_emb, const float* __restrict__ sp_emb_rev,
    u16* __restrict__ ab)                // [1536][768] bf16
{
  __shared__ __align__(16) u16 Kt[384][32];   // [m][d(24)+pad]
  __shared__ __align__(16) u16 Vt[32][392];   // [d(24)+pad][m] transposed
  __shared__ __align__(16) u16 Qt[64][32];
  __shared__ __align__(16) u16 Pw[4][16][32]; // per-wave P chunk
  __shared__ float spc[512], sprc[512];
  const int bid = blockIdx.x;
  const int pair = bid % 3;
  const int h = (bid / 3) % Hh;
  const int b = bid / (3 * Hh);
  const int t = threadIdx.x, lane = t & 63, wave = t >> 6;
  const int ql = lane & 15, hi = lane >> 4;

  for (int idx = t; idx < 384*6; idx += 256) {
    const int m = idx / 6, c = idx - m*6;
    const u16* base = qkv + ((size_t)m*Bb + b)*2304 + h*24 + c*4;
    uint2 kk = *(const uint2*)(base + 768);
    uint2 vv = *(const uint2*)(base + 1536);
    *(uint2*)&Kt[m][c*4] = kk;
    Vt[c*4+0][m] = (u16)(vv.x & 0xffffu); Vt[c*4+1][m] = (u16)(vv.x >> 16);
    Vt[c*4+2][m] = (u16)(vv.y & 0xffffu); Vt[c*4+3][m] = (u16)(vv.y >> 16);
  }
  for (int idx = t; idx < 384*2; idx += 256)           // K d-pad
    *(uint2*)&Kt[idx>>1][24 + (idx&1)*4] = make_uint2(0u, 0u);
  for (int idx = t; idx < 8*196; idx += 256)           // V^T d-pad rows
    *(unsigned*)((char*)&Vt[24][0] + idx*4) = 0u;
  for (int idx = t; idx < 64*2; idx += 256)            // Q d-pad
    *(uint2*)&Qt[idx>>1][24 + (idx&1)*4] = make_uint2(0u, 0u);
  if (!PREBIAS) {
    for (int i = t; i < 512; i += 256) {
      spc[i]  = sp_emb[(size_t)i*Hh + h];
      sprc[i] = sp_emb_rev[(size_t)i*Hh + h];
    }
  }

  for (int qi = 0; qi < 2; ++qi) {
    const int ntile = pair*2 + qi;
    for (int idx = t; idx < 64*6; idx += 256) {
      const int qr = idx / 6, c = idx - qr*6;
      const u16* base = qkv + ((size_t)(ntile*64 + qr)*Bb + b)*2304 + h*24 + c*4;
      *(uint2*)&Qt[qr][c*4] = *(const uint2*)base;
    }
    __syncthreads();   // covers K/V staging (iter 0) and Qt restage

    const int q0 = ntile*64 + wave*16;
    const int q = q0 + ql;
    const bf16x8 qf = *(const bf16x8*)&Qt[wave*16 + ql][hi*8];

    f32x4 f[24];
    const u16* bp = biasb + (((size_t)(b*Hh + h)*24 + ntile*4 + wave)*24)*256 + lane*4;
    const size_t crow = ((size_t)b*Nn + q)*Nn;
    #pragma unroll
    for (int tt = 0; tt < 24; ++tt) {
      bf16x8 kf = *(const bf16x8*)&Kt[tt*16 + ql][hi*8];
      f32x4 z = (f32x4){0.f,0.f,0.f,0.f};
      f32x4 s = __builtin_amdgcn_mfma_f32_16x16x32_bf16(kf, qf, z, 0, 0, 0);
      if (PREBIAS) {
        uint2 bb = *(const uint2*)(bp + tt*256);
        s[0] += b2f((u16)(bb.x & 0xffffu)); s[1] += b2f((u16)(bb.x >> 16));
        s[2] += b2f((u16)(bb.y & 0xffffu)); s[3] += b2f((u16)(bb.y >> 16));
      } else {
        const int off = tt*16 + hi*4;
        int4 s4 = *(const int4*)(sp + crow + off);
        int4 t4 = *(const int4*)(spT + crow + off);
        float4 a4 = *(const float4*)(atb + crow + off);
        s[0] += a4.x + spc[s4.x] + sprc[t4.x];
        s[1] += a4.y + spc[s4.y] + sprc[t4.y];
        s[2] += a4.z + spc[s4.z] + sprc[t4.z];
        s[3] += a4.w + spc[s4.w] + sprc[t4.w];
      }
      f[tt] = s;
    }

    float mx = -3.0e38f;
    #pragma unroll
    for (int tt = 0; tt < 24; ++tt)
      mx = fmaxf(mx, fmaxf(fmaxf(f[tt][0], f[tt][1]), fmaxf(f[tt][2], f[tt][3])));
    mx = fmaxf(mx, __shfl_xor(mx, 16, 64));
    mx = fmaxf(mx, __shfl_xor(mx, 32, 64));
    float sum = 0.f;
    #pragma unroll
    for (int tt = 0; tt < 24; ++tt) {
      #pragma unroll
      for (int j = 0; j < 4; ++j) { f[tt][j] = __expf(f[tt][j] - mx); sum += f[tt][j]; }
    }
    sum += __shfl_xor(sum, 16, 64);
    sum += __shfl_xor(sum, 32, 64);
    const float inv = 1.0f / sum;

    f32x4 o0 = (f32x4){0.f,0.f,0.f,0.f}, o1 = (f32x4){0.f,0.f,0.f,0.f};
    char* prow = (char*)&Pw[wave][ql][0];
    const int swz = (ql & 3) << 4;
    #pragma unroll
    for (int c = 0; c < 12; ++c) {
      unsigned w0 = pkcvt(f[2*c][0],   f[2*c][1]);
      unsigned w1 = pkcvt(f[2*c][2],   f[2*c][3]);
      unsigned w2 = pkcvt(f[2*c+1][0], f[2*c+1][1]);
      unsigned w3 = pkcvt(f[2*c+1][2], f[2*c+1][3]);
      *(unsigned*)(prow + (((hi*8)      ) ^ swz)) = w0;
      *(unsigned*)(prow + (((hi*8) +  4) ^ swz)) = w1;
      *(unsigned*)(prow + (((hi*8) + 32) ^ swz)) = w2;
      *(unsigned*)(prow + (((hi*8) + 36) ^ swz)) = w3;
      bf16x8 a = *(const bf16x8*)(prow + ((hi*16) ^ swz));
      bf16x8 v0 = *(const bf16x8*)&Vt[ql][c*32 + hi*8];
      bf16x8 v1 = *(const bf16x8*)&Vt[16 + ql][c*32 + hi*8];
      o0 = __builtin_amdgcn_mfma_f32_16x16x32_bf16(a, v0, o0, 0, 0, 0);
      o1 = __builtin_amdgcn_mfma_f32_16x16x32_bf16(a, v1, o1, 0, 0, 0);
    }

    #pragma unroll
    for (int j = 0; j < 4; ++j) {
      float invj = __shfl(inv, hi*4 + j, 64);
      const int qg = q0 + hi*4 + j;
      u16* orow = ab + ((size_t)qg*Bb + b)*Ee + h*24;
      orow[ql] = f2b(o0[j] * invj);
      if (ql < 8) orow[16 + ql] = f2b(o1[j] * invj);
    }
    __syncthreads();   // protect Qt/Pw before restage
  }
}

// ---------------- residual + LayerNorm: wave-per-row, no block barriers, float4 loads
template<int NP>
__global__ __launch_bounds__(256) void ln_kernel(
    const float* __restrict__ xin, const float* __restrict__ delta,
    const float* __restrict__ gamma, const float* __restrict__ beta,
    float* __restrict__ xout, u16* __restrict__ xb)
{
  const int wave = threadIdx.x >> 6, lane = threadIdx.x & 63;
  const int r = blockIdx.x * 4 + wave;
  const size_t base = (size_t)r * Ee;
  const int c0 = lane * 12;
  float v[12];
  #pragma unroll
  for (int i = 0; i < 3; ++i) {
    float4 xv = *(const float4*)(xin + base + c0 + i*4);
    v[i*4+0] = xv.x; v[i*4+1] = xv.y; v[i*4+2] = xv.z; v[i*4+3] = xv.w;
  }
  #pragma unroll
  for (int p = 0; p < NP; ++p) {
    const float* dp = delta + (size_t)p*(Mm*768) + base + c0;
    #pragma unroll
    for (int i = 0; i < 3; ++i) {
      float4 dv = *(const float4*)(dp + i*4);
      v[i*4+0] += dv.x; v[i*4+1] += dv.y; v[i*4+2] += dv.z; v[i*4+3] += dv.w;
    }
  }
  float s = 0.f;
  #pragma unroll
  for (int i = 0; i < 12; ++i) s += v[i];
  #pragma unroll
  for (int off = 1; off < 64; off <<= 1) s += __shfl_xor(s, off, 64);
  const float mean = s * (1.0f / 768.0f);
  float qs = 0.f;
  #pragma unroll
  for (int i = 0; i < 12; ++i) { float d = v[i] - mean; qs += d * d; }
  #pragma unroll
  for (int off = 1; off < 64; off <<= 1) qs += __shfl_xor(qs, off, 64);
  const float rstd = rsqrtf(qs * (1.0f / 768.0f) + 1e-5f);
  float o[12];
  #pragma unroll
  for (int i = 0; i < 3; ++i) {
    float4 g4 = *(const float4*)(gamma + c0 + i*4);
    float4 b4 = *(const float4*)(beta + c0 + i*4);
    o[i*4+0] = (v[i*4+0] - mean) * rstd * g4.x + b4.x;
    o[i*4+1] = (v[i*4+1] - mean) * rstd * g4.y + b4.y;
    o[i*4+2] = (v[i*4+2] - mean) * rstd * g4.z + b4.z;
    o[i*4+3] = (v[i*4+3] - mean) * rstd * g4.w + b4.w;
    *(float4*)(xout + base + c0 + i*4) = make_float4(o[i*4+0], o[i*4+1], o[i*4+2], o[i*4+3]);
  }
  #pragma unroll
  for (int i = 0; i < 3; ++i) {
    uint2 u;
    u.x = pkcvt(o[i*4+0], o[i*4+1]);
    u.y = pkcvt(o[i*4+2], o[i*4+3]);
    *(uint2*)(xb + base + c0 + i*4) = u;
  }
}

extern "C" void kernel_launch(void* const* d_in, const int* in_sizes, int n_in,
                              void* d_out, int out_size, void* d_ws, size_t ws_size,
                              hipStream_t stream) {
  const int*   node_type  = (const int*)d_in[0];
  const float* nif        = (const float*)d_in[1];
  const int*   in_deg     = (const int*)d_in[2];
  const int*   out_deg    = (const int*)d_in[3];
  const float* atb        = (const float*)d_in[4];
  const int*   sp         = (const int*)d_in[5];
  const float* node_emb   = (const float*)d_in[6];
  const float* ind_emb    = (const float*)d_in[7];
  const float* outd_emb   = (const float*)d_in[8];
  const float* sp_emb     = (const float*)d_in[9];
  const float* sp_emb_rev = (const float*)d_in[10];
  const float* Wq = (const float*)d_in[11]; const float* bq = (const float*)d_in[12];
  const float* Wk = (const float*)d_in[13]; const float* bk = (const float*)d_in[14];
  const float* Wv = (const float*)d_in[15]; const float* bv = (const float*)d_in[16];
  const float* Wo = (const float*)d_in[17]; const float* bo = (const float*)d_in[18];
  const float* W1 = (const float*)d_in[19]; const float* b1 = (const float*)d_in[20];
  const float* W2 = (const float*)d_in[21]; const float* b2 = (const float*)d_in[22];
  const float* ln1s = (const float*)d_in[23]; const float* ln1b = (const float*)d_in[24];
  const float* ln2s = (const float*)d_in[25]; const float* ln2b = (const float*)d_in[26];

  char* ws = (char*)d_ws;
  float* x      = (float*)(ws);                    //  4,718,592
  u16*   xb     = (u16*)(ws +  4718592);           //  2,359,296
  u16*   qkvb16 = (u16*)(ws +  7077888);           //  7,077,888
  u16*   abuf   = (u16*)(ws + 14155776);           //  2,359,296
  u16*   hb     = (u16*)(ws + 16515072);           //  9,437,184
  float* obufP  = (float*)(ws + 25952256);         // 18,874,368 (4 partials)
  int*   spTb   = (int*)(ws + 44826624);           //  2,359,296
  u16*   biasb  = (u16*)(ws + 47185920);           // 37,748,736 -> 84,934,656
  u16*   wTslot = (u16*)(ws + 84934656);           // 14,155,776 (one layer slot)
  const bool useBias = ws_size >= 99090432ull;

  embed_kernel<<<Mm, 256, 0, stream>>>(node_type, nif, in_deg, out_deg,
                                       node_emb, ind_emb, outd_emb, x, xb);
  spT_kernel<<<dim3(12, 12, 4), dim3(32, 8), 0, stream>>>(sp, spTb);
  if (useBias)
    bias_pre_kernel<<<dim3(24, 32, 4), 256, 0, stream>>>(atb, sp, spTb, sp_emb, sp_emb_rev, biasb);

  const float scaleQ = 0.2041241452319315f;  // 24^-0.5

  for (int l = 0; l < Ll; ++l) {
    const float *bql = bq + (size_t)l*Ee, *bkl = bk + (size_t)l*Ee, *bvl = bv + (size_t)l*Ee;
    const float *bol = bo + (size_t)l*Ee;
    const float *b1l = b1 + (size_t)l*Ff, *b2l = b2 + (size_t)l*Ee;

    // per-layer weight transpose+convert: slot stays L3-hot for this layer's GEMMs
    wconv_kernel<<<1728, 256, 0, stream>>>(Wq, Wk, Wv, Wo, W1, W2, l, wTslot);
    const u16* qkvT = wTslot;
    const u16* woT  = wTslot + 1769472;
    const u16* w1T  = wTslot + 2359296;
    const u16* w2T  = wTslot + 4718592;

    // QKV: [1536,768] @ [2304,768]^T -> bf16 [1536][2304]
    gemm3_kernel<0><<<dim3(12, 36), 256, 0, stream>>>(xb, qkvT, bql, bkl, bvl,
                                                      768, 768, scaleQ, nullptr, qkvb16);
    if (useBias)
      attn2_kernel<1><<<384, 256, 0, stream>>>(qkvb16, biasb, atb, sp, spTb,
                                               sp_emb, sp_emb_rev, abuf);
    else
      attn2_kernel<0><<<384, 256, 0, stream>>>(qkvb16, nullptr, atb, sp, spTb,
                                               sp_emb, sp_emb_rev, abuf);
    // O-proj: split-K 2 -> partials
    gemm3_kernel<1><<<dim3(12, 12, 2), 256, 0, stream>>>(abuf, woT, bol, bol, bol,
                                                         768, 384, 1.0f, obufP, nullptr);
    ln_kernel<2><<<Mm/4, 256, 0, stream>>>(x, obufP, ln1s + (size_t)l*Ee, ln1b + (size_t)l*Ee, x, xb);
    // FFN1 + gelu -> bf16 hidden
    gemm3_kernel<2><<<dim3(12, 48), 256, 0, stream>>>(xb, w1T, b1l, b1l, b1l,
                                                      768, 768, 1.0f, nullptr, hb);
    // FFN2: split-K 4 -> partials
    gemm3_kernel<1><<<dim3(12, 12, 4), 256, 0, stream>>>(hb, w2T, b2l, b2l, b2l,
                                                         3072, 768, 1.0f, obufP, nullptr);
    float* xdst = (l == Ll - 1) ? (float*)d_out : x;
    ln_kernel<4><<<Mm/4, 256, 0, stream>>>(x, obufP, ln2s + (size_t)l*Ee, ln2b + (size_t)l*Ee, xdst, xb);
  }
}